// Round 3
// baseline (210.412 us; speedup 1.0000x reference)
//
#include <hip/hip_runtime.h>
#include <limits.h>

// Camera back-projection R3: per-(n,iy,iz-half) LDS-staged depth bounding box.
//
// out[n,0,ix,iy,iz] = 1 - 128*tdf ; tdf = min(|zc-d|,1/128) if in-frustum else 1/128
// u = (fl*x)/zc + 239.5 depends on (ix,iz); v = (fl*y)/zc + 239.5 on (iy,iz).
//
// For fixed (n,iy) and a 64-iz half, needed pixels live in a bbox of
// <=30 rows (fl*|y|max*(1/zc_min-1/zc_max) ~ 27.5 px) x <=246 cols
// (u full span at zc_min ~ 244 px). Stage the bbox into LDS with coalesced
// row loads; gathers become LDS reads (TW=253 odd -> bank-spread). Lanes walk
// iz so global stores are 64 consecutive floats/wave (fully coalesced), no
// transpose. One exact IEEE div per output; per-iz v/zc precomputed by 64
// threads. Bounds via monotonicity of u in x (endpoint reduce w/ LDS atomics).
//
// Numerics: exact '/' + rintf(half-to-even) -> bit-exact vs numpy (absmax 0.0
// in R1/R2). No reciprocal shortcuts anywhere a rounding decision depends on.

#define RES 128
#define IMG 480
#define TW  253   // tile cols allocated (odd: gcd(253,32)=1, spreads banks)
#define TR  32    // tile rows allocated (worst case ~30)

__global__ __launch_bounds__(256) void cbp_kernel(
    const float* __restrict__ depth,
    const float* __restrict__ fl,
    const float* __restrict__ cam_dist,
    float* __restrict__ out)
{
    __shared__ float s_img[TR * TW];   // 32,384 B
    __shared__ float s_zc[64];
    __shared__ int   s_vrow[64];       // phase A: vi ; phase B: (vi-vmin)*TW
    __shared__ int   s_vok[64];
    __shared__ int   s_umin, s_umax, s_vmin, s_vmax;

    const int b    = blockIdx.x;
    const int half = b & 1;            // iz in [half*64, half*64+64)
    const int iy   = (b >> 1) & (RES - 1);
    const int n    = b >> 8;
    const int t    = threadIdx.x;

    const float flv = fl[n];
    const float cd  = cam_dist[n];

    if (t == 0) { s_umin = INT_MAX; s_umax = INT_MIN; s_vmin = INT_MAX; s_vmax = INT_MIN; }
    __syncthreads();

    // ---- phase A: per-iz (64 threads) zc, v, vi, validity, u endpoint bounds ----
    if (t < 64) {
        const int   iz = half * 64 + t;
        const float z  = (iz + 0.5f) / 128.0f - 0.5f;
        const float zc = cd - z;
        const float y  = (iy + 0.5f) / 128.0f - 0.5f;
        const float fy = flv * y;
        const float v  = fy / zc + (float)(IMG - 1) * 0.5f;     // exact IEEE
        const float vr = rintf(v);
        const int   vi = (int)fminf(fmaxf(vr, 0.0f), (float)(IMG - 1));
        s_zc[t]   = zc;
        s_vrow[t] = vi;
        s_vok[t]  = (v >= 0.0f) && (v <= (float)(IMG - 1)) && (zc > 0.0f);

        // u is monotone in x for zc>0 (reversed for zc<0) -> endpoints bound all ix
        const float x0  = (0.0f   + 0.5f) / 128.0f - 0.5f;
        const float x1  = (127.0f + 0.5f) / 128.0f - 0.5f;
        const float ua  = (flv * x0) / zc + (float)(IMG - 1) * 0.5f;
        const float ub  = (flv * x1) / zc + (float)(IMG - 1) * 0.5f;
        const int   ia  = (int)fminf(fmaxf(rintf(ua), 0.0f), (float)(IMG - 1));
        const int   ib  = (int)fminf(fmaxf(rintf(ub), 0.0f), (float)(IMG - 1));
        atomicMin(&s_umin, min(ia, ib));
        atomicMax(&s_umax, max(ia, ib));
        atomicMin(&s_vmin, vi);
        atomicMax(&s_vmax, vi);
    }
    __syncthreads();

    const int umin = s_umin, vmin = s_vmin;
    const int Wt = s_umax - umin + 1;          // <= 246
    const int Rt = s_vmax - vmin + 1;          // <= 30

    // ---- phase B: stage bbox rows into LDS (coalesced), fix vrow ----
    {
        const float* __restrict__ dimg = depth + (size_t)n * (IMG * IMG);
        const int wave = t >> 6, lane = t & 63;
        const int Rc = min(Rt, TR), Wc = min(Wt, TW);
        for (int r = wave; r < Rc; r += 4) {
            const float* __restrict__ src = dimg + (size_t)(vmin + r) * IMG + umin;
            float* __restrict__ dst = &s_img[r * TW];
            for (int c = lane; c < Wc; c += 64) dst[c] = src[c];
        }
        if (t < 64) s_vrow[t] = (s_vrow[t] - vmin) * TW;
    }
    __syncthreads();

    // ---- phase C: compute + store; lanes walk iz -> coalesced stores ----
    const int   izl  = t & 63;
    const int   w    = t >> 6;
    const float zc   = s_zc[izl];
    const int   vrow = s_vrow[izl];
    const int   vok  = s_vok[izl];
    const float trunc = 1.0f / 128.0f;

    float* __restrict__ obase =
        out + ((size_t)n * RES) * (RES * RES) + (size_t)iy * RES + half * 64 + izl;

#pragma unroll 4
    for (int k = 0; k < 32; ++k) {
        const int   ix = w * 32 + k;
        const float x  = (ix + 0.5f) / 128.0f - 0.5f;
        const float fx = flv * x;
        const float u  = fx / zc + (float)(IMG - 1) * 0.5f;     // exact IEEE
        const float ur = rintf(u);
        const int   ui = (int)fminf(fmaxf(ur, 0.0f), (float)(IMG - 1));
        const float d  = s_img[vrow + (ui - umin)];
        const bool ok  = vok && (u >= 0.0f) && (u <= (float)(IMG - 1)) && (d > 0.0f);
        float tdf = fminf(fabsf(zc - d), trunc);
        tdf = ok ? tdf : trunc;
        obase[(size_t)ix * (RES * RES)] = 1.0f - 128.0f * tdf;
    }
}

extern "C" void kernel_launch(void* const* d_in, const int* in_sizes, int n_in,
                              void* d_out, int out_size, void* d_ws, size_t ws_size,
                              hipStream_t stream) {
    const float* depth = (const float*)d_in[0];
    const float* fl    = (const float*)d_in[1];
    const float* cd    = (const float*)d_in[2];
    float* out         = (float*)d_out;

    const int N = in_sizes[1];                 // fl is (N,1)
    const int grid = N * RES * 2;              // (n, iy, iz-half)
    cbp_kernel<<<grid, 256, 0, stream>>>(depth, fl, cd, out);
}

// Round 4
// 170.680 us; speedup vs baseline: 1.2328x; 1.2328x over previous
//
#include <hip/hip_runtime.h>

// Camera back-projection R4: wave-private tiles, no cross-wave coupling.
//
// One 64-thread block per tile (n, iy, ix-half, iz-quarter) = 64 ix x 32 iz.
// Compute phase: lanes = ix -> per gather instr u spans ~100px on ONE image
// row (v is wave-uniform per iz) = 3-4 cache lines, vs ~40+ scattered in R1.
// Per-iz zc / v-row / v-valid computed once by lanes 0..31 (1 IEEE div),
// broadcast from LDS. Results transposed through a wave-private LDS tile
// (row stride 36 words: both ds_write_b128 and ds_read_b128 phases hit the
// even 8-words-per-bank floor -> no conflicts beyond the b128 minimum).
// Store phase: 8 instrs, each 8 ix-rows x 32 iz = 8 full 128B lines (1KB),
// matching fillBuffer-grade store efficiency (it gets 6.75 TB/s).
// Single-wave blocks: __syncthreads is just a waitcnt (launch_bounds 64),
// so none of R2/R3's barrier/staging serialization.
//
// Numerics: exact IEEE '/' + rintf (half-to-even), same op order as the
// reference -> bit-exact (absmax 0.0 in R1-R3).

#define RES 128
#define IMG 480
#define ST  36   // LDS tile row stride in words (32 iz + 4 pad, 16B-aligned)

__global__ __launch_bounds__(64) void cbp_kernel(
    const float* __restrict__ depth,
    const float* __restrict__ fl,
    const float* __restrict__ cam_dist,
    float* __restrict__ out)
{
    __shared__ float s_tile[64 * ST];   // 9216 B
    __shared__ float s_zc[32];
    __shared__ int   s_vrow[32];
    __shared__ int   s_vok[32];

    const int b   = blockIdx.x;
    const int izb = b & 3;              // iz quarter: iz in [izb*32, izb*32+32)
    const int ixh = (b >> 2) & 1;       // ix half
    const int iy  = (b >> 3) & (RES - 1);
    const int n   = b >> 10;
    const int l   = threadIdx.x;

    const float flv = fl[n];
    const float cd  = cam_dist[n];

    // ---- per-iz precompute (lanes 0..31): zc, v row, v validity ----
    if (l < 32) {
        const int   iz = izb * 32 + l;
        const float z  = (iz + 0.5f) / 128.0f - 0.5f;
        const float zc = cd - z;
        const float y  = (iy + 0.5f) / 128.0f - 0.5f;
        const float v  = (flv * y) / zc + 239.5f;   // exact IEEE div
        const float vr = rintf(v);                  // half-to-even == np.round
        const int   vi = (int)fminf(fmaxf(vr, 0.0f), 479.0f);
        s_zc[l]   = zc;
        s_vrow[l] = vi * IMG;
        s_vok[l]  = (v >= 0.0f) && (v <= 479.0f) && (zc > 0.0f);
    }
    __syncthreads();   // single-wave block -> compiles to a waitcnt

    // ---- compute phase: lanes = ix, gathers ride one image row ----
    const int   ix = ixh * 64 + l;
    const float x  = (ix + 0.5f) / 128.0f - 0.5f;
    const float fx = flv * x;
    const float* __restrict__ dimg = depth + (size_t)n * (IMG * IMG);
    const float trunc = 1.0f / 128.0f;

#pragma unroll 2
    for (int g = 0; g < 8; ++g) {
        float4 r;
        float* rp = &r.x;
#pragma unroll
        for (int j = 0; j < 4; ++j) {
            const int   jj = g * 4 + j;           // iz within tile
            const float zc = s_zc[jj];            // broadcast read
            const float u  = fx / zc + 239.5f;    // exact IEEE div
            const float ur = rintf(u);
            const int   ui = (int)fminf(fmaxf(ur, 0.0f), 479.0f);
            const float d  = dimg[s_vrow[jj] + ui];
            const bool ok  = s_vok[jj] && (u >= 0.0f) && (u <= 479.0f) && (d > 0.0f);
            float tdf = fminf(fabsf(zc - d), trunc);
            tdf = ok ? tdf : trunc;
            rp[j] = 1.0f - 128.0f * tdf;
        }
        *(float4*)&s_tile[l * ST + g * 4] = r;    // ds_write_b128, even bank spread
    }
    __syncthreads();   // waitcnt only

    // ---- store phase: 8 instrs x (8 ix rows x 32 iz) = 8 full lines each ----
    const size_t obase = ((size_t)(n * RES + ixh * 64) * RES + iy) * RES + izb * 32;
    const int h = l >> 3;       // ix sub-row 0..7
    const int q = l & 7;        // iz quad 0..7
#pragma unroll
    for (int s = 0; s < 8; ++s) {
        const int ixl = s * 8 + h;
        const float4 val = *(const float4*)&s_tile[ixl * ST + q * 4];
        *(float4*)&out[obase + (size_t)ixl * (RES * RES) + q * 4] = val;
    }
}

extern "C" void kernel_launch(void* const* d_in, const int* in_sizes, int n_in,
                              void* d_out, int out_size, void* d_ws, size_t ws_size,
                              hipStream_t stream) {
    const float* depth = (const float*)d_in[0];
    const float* fl    = (const float*)d_in[1];
    const float* cd    = (const float*)d_in[2];
    float* out         = (float*)d_out;

    const int N = in_sizes[1];                  // fl is (N,1)
    const int grid = N * RES * 2 * 4;           // (n, iy, ixh, izb)
    cbp_kernel<<<grid, 64, 0, stream>>>(depth, fl, cd, out);
}

// Round 5
// 170.550 us; speedup vs baseline: 1.2337x; 1.0008x over previous
//
#include <hip/hip_runtime.h>

// Camera back-projection R5: separability tables + XCD-local depth residency.
//
// u = fl*x/zc + 239.5 depends ONLY on (n,ix,iz); v on (n,iy,iz). R4 computed
// 33.5M IEEE-div chains; only 2x262k are distinct. Prologue kernel builds
//   U[n][iz][ix] = ui | (uok<<15)          (ushort, 512KB)
//   V[n][iy][iz] = vok ? vi*480 | 1<<30 : 0 (int, 1MB)
// with bit-identical expressions (exact '/' + rintf half-to-even; absmax 0.0
// every round so far). Main kernel (R4 wave-private-tile skeleton) then does
// ~10 VALU + 2 cached loads per element, no div latency.
//
// XCD swizzle: xcd = blk&7 handles images {2*xcd, 2*xcd+1} -> 1.84MB depth
// per XCD, resident in its 4MB L2: gathers become ~200cyc L2 hits instead of
// ~900cyc HBM misses, and depth is fetched from HBM ~once per XCD.
//
// Stores unchanged from R4: LDS-transposed, 8 full 128B lines per instr.

#define RES  128
#define IMG  480
#define ST   36      // tile row stride (words): b128 phases hit the 8-word/bank floor
#define MAXN 32

__device__ unsigned short g_U[MAXN * RES * RES];  // [n][iz][ix]
__device__ int            g_V[MAXN * RES * RES];  // [n][iy][iz]

__global__ __launch_bounds__(256) void cbp_tables(
    const float* __restrict__ fl, const float* __restrict__ cam_dist, int total)
{
    int t = blockIdx.x * 256 + threadIdx.x;
    if (t >= total) return;
    const int n = t >> 14;          // 16384 entries per n
    const int a = (t >> 7) & 127;   // iz for U, iy for V
    const int c = t & 127;          // ix for U, iz for V
    const float flv = fl[n], cd = cam_dist[n];

    {   // U entry (n, iz=a, ix=c) — exact same op order as reference
        const float zc = cd - ((a + 0.5f) / 128.0f - 0.5f);
        const float x  = (c + 0.5f) / 128.0f - 0.5f;
        const float u  = (flv * x) / zc + 239.5f;     // IEEE div
        const int   ui = (int)fminf(fmaxf(rintf(u), 0.0f), 479.0f);
        const int  uok = (u >= 0.0f) && (u <= 479.0f);
        g_U[t] = (unsigned short)(ui | (uok << 15));
    }
    {   // V entry (n, iy=a, iz=c)
        const float zc = cd - ((c + 0.5f) / 128.0f - 0.5f);
        const float y  = (a + 0.5f) / 128.0f - 0.5f;
        const float v  = (flv * y) / zc + 239.5f;     // IEEE div
        const int   vi = (int)fminf(fmaxf(rintf(v), 0.0f), 479.0f);
        const int  vok = (v >= 0.0f) && (v <= 479.0f) && (zc > 0.0f);
        g_V[t] = vok ? ((vi * IMG) | (1 << 30)) : 0;
    }
}

__global__ __launch_bounds__(64) void cbp_main(
    const float* __restrict__ depth, const float* __restrict__ cam_dist,
    float* __restrict__ out, int N)
{
    __shared__ __align__(16) float s_tile[64 * ST];   // 9216 B, wave-private
    __shared__ float s_zc[32];
    __shared__ int   s_pv[32];

    const int b = blockIdx.x;
    int n, iy, ixh, izb;
    if (N == 16) {                    // XCD-local: 2 images per XCD
        const int xcd = b & 7, i = b >> 3;
        n = xcd * 2 + (i >> 10);
        const int rr = i & 1023;
        iy = rr >> 3; ixh = (rr >> 2) & 1; izb = rr & 3;
    } else {
        izb = b & 3; ixh = (b >> 2) & 1; iy = (b >> 3) & 127; n = b >> 10;
    }
    const int l = threadIdx.x;
    const float cd = cam_dist[n];

    if (l < 32) {                     // per-iz broadcast data
        const int iz = izb * 32 + l;
        s_zc[l] = cd - ((iz + 0.5f) / 128.0f - 0.5f);
        s_pv[l] = g_V[((n << 7) + iy) * 128 + iz];
    }
    __syncthreads();                  // single-wave block -> waitcnt only

    const float* __restrict__ dimg = depth + (size_t)n * (IMG * IMG);
    const int ix = ixh * 64 + l;
    const unsigned short* __restrict__ Urow = &g_U[((n << 7) + izb * 32) * 128 + ix];
    const float trunc = 1.0f / 128.0f;

#pragma unroll
    for (int g = 0; g < 8; ++g) {
        float4 r; float* rp = &r.x;
#pragma unroll
        for (int j = 0; j < 4; ++j) {
            const int   jj = g * 4 + j;
            const float zc = s_zc[jj];              // LDS broadcast
            const int   pv = s_pv[jj];              // LDS broadcast
            const int   pu = Urow[jj * 128];        // 128B coalesced, L1/L2-hot
            const int   ui = pu & 0x1FF;
            const int   vrow = pv & 0x3FFFF;        // vi*480 < 2^18
            const int   okuv = ((pv >> 30) & 1) & (pu >> 15);
            const float d  = dimg[vrow + ui];       // L2-resident gather
            const bool  ok = okuv && (d > 0.0f);
            const float tdf = fminf(fabsf(zc - d), trunc);
            rp[j] = ok ? (1.0f - 128.0f * tdf) : 0.0f;  // 1-128*trunc == 0
        }
        *(float4*)&s_tile[l * ST + g * 4] = r;      // b128, 8-word/bank floor
    }
    __syncthreads();

    // store: 8 instrs x (8 ix-rows x 32 iz) = 8 full 128B lines each
    const size_t obase = ((size_t)(n * RES + ixh * 64) * RES + iy) * RES + izb * 32;
    const int h = l >> 3, q = l & 7;
#pragma unroll
    for (int s = 0; s < 8; ++s) {
        const int ixl = s * 8 + h;
        *(float4*)&out[obase + (size_t)ixl * (RES * RES) + q * 4] =
            *(const float4*)&s_tile[ixl * ST + q * 4];
    }
}

extern "C" void kernel_launch(void* const* d_in, const int* in_sizes, int n_in,
                              void* d_out, int out_size, void* d_ws, size_t ws_size,
                              hipStream_t stream) {
    const float* depth = (const float*)d_in[0];
    const float* fl    = (const float*)d_in[1];
    const float* cd    = (const float*)d_in[2];
    float* out         = (float*)d_out;

    const int N = in_sizes[1];                 // fl is (N,1); harness uses 16
    const int tab_total = N * RES * RES;
    cbp_tables<<<(tab_total + 255) / 256, 256, 0, stream>>>(fl, cd, tab_total);

    const int grid = N * RES * 2 * 4;          // (n, iy, ixh, izb)
    cbp_main<<<grid, 64, 0, stream>>>(depth, cd, out, N);
}

// Round 6
// 167.684 us; speedup vs baseline: 1.2548x; 1.0171x over previous
//
#include <hip/hip_runtime.h>

// Camera back-projection R6: contiguous-store tiles (DRAM-friendly writes).
//
// R1/R4/R5 all converge at ~60us kernel time with 131MB stores at only
// ~2.3 TB/s (fillBuffer: 6.5 TB/s). Their store instrs emit 128B lines at
// 64KB stride (ix-major output) -> random-128B DRAM write stream -> row
// thrash. R6 tiles the output as (n, 16 ix, 4 iy, 128 iz): each (ix,4iy)
// span is 2KB CONTIGUOUS; every wave store instr writes 1KB = 8 consecutive
// 128B lines. Compute keeps lanes = 16 ix x 4 iy (u spans ~27px on 4 rows
// -> ~4-8 lines/gather, like R4), iz wave-uniform per step.
//
// Tables (from R5, bit-exact): U[n][iz][ix] = ui|(uok<<15) ushort;
// V[n][iy][iz] = vi*480|(vok<<30) int. Exact IEEE '/' + rintf half-to-even
// -> absmax 0.0 in all rounds. XCD swizzle keeps 2 depth images (1.8MB)
// L2-resident per XCD.
//
// LDS tile row stride 132 floats (33 float4s): wave64 b128 write (uniform
// iz0, rows 0..63: a%32 = 4*row+iz0 -> 8 addr classes x 4 banks = all 32
// banks, 8 words/bank = the b128 floor, conflict-free) and read (same) both
// optimal. s_pv stride 129 -> 4-address broadcast, free.

#define RES  128
#define IMG  480
#define MAXN 32
#define TS   132    // tile row stride in floats

__device__ unsigned short g_U[MAXN * RES * RES];  // [n][iz][ix]
__device__ int            g_V[MAXN * RES * RES];  // [n][iy][iz]

__global__ __launch_bounds__(256) void cbp_tables(
    const float* __restrict__ fl, const float* __restrict__ cam_dist, int total)
{
    int t = blockIdx.x * 256 + threadIdx.x;
    if (t >= total) return;
    const int n = t >> 14;
    const int a = (t >> 7) & 127;   // iz for U, iy for V
    const int c = t & 127;          // ix for U, iz for V
    const float flv = fl[n], cd = cam_dist[n];
    {   // U (n, iz=a, ix=c) — same op order as reference
        const float zc = cd - ((a + 0.5f) / 128.0f - 0.5f);
        const float x  = (c + 0.5f) / 128.0f - 0.5f;
        const float u  = (flv * x) / zc + 239.5f;          // exact IEEE div
        const int   ui = (int)fminf(fmaxf(rintf(u), 0.0f), 479.0f);
        const int  uok = (u >= 0.0f) && (u <= 479.0f);
        g_U[t] = (unsigned short)(ui | (uok << 15));
    }
    {   // V (n, iy=a, iz=c)
        const float zc = cd - ((c + 0.5f) / 128.0f - 0.5f);
        const float y  = (a + 0.5f) / 128.0f - 0.5f;
        const float v  = (flv * y) / zc + 239.5f;          // exact IEEE div
        const int   vi = (int)fminf(fmaxf(rintf(v), 0.0f), 479.0f);
        const int  vok = (v >= 0.0f) && (v <= 479.0f) && (zc > 0.0f);
        g_V[t] = vok ? ((vi * IMG) | (1 << 30)) : 0;
    }
}

__global__ __launch_bounds__(256) void cbp_main(
    const float* __restrict__ depth, const float* __restrict__ cam_dist,
    float* __restrict__ out, int N)
{
    __shared__ __align__(16) float s_tile[64 * TS];   // 33,792 B
    __shared__ int   s_pv[4 * 129];                   // 4 iy rows, stride 129
    __shared__ float s_zc[RES];

    const int b = blockIdx.x;
    int n, r;
    if (N == 16) {                  // XCD-local: 2 images per XCD
        const int xcd = b & 7, i = b >> 3;
        n = xcd * 2 + (i >> 8);
        r = i & 255;
    } else {
        n = b >> 8; r = b & 255;
    }
    const int ixg = r & 7;          // 16-ix group
    const int iyg = r >> 3;         // 4-iy group
    const int l   = threadIdx.x;
    const int ix_l = l & 15;
    const int iy_l = (l >> 4) & 3;
    const int izq  = l >> 6;        // == wave id -> iz wave-uniform per step
    const float cd = cam_dist[n];

    if (l < 128) s_zc[l] = cd - ((l + 0.5f) / 128.0f - 0.5f);
    {   // V rows for iy = iyg*4 .. +3 : 512 consecutive ints, 2 coalesced loads
        const int base = (n << 14) + (iyg << 9);
        int e = l;
        s_pv[(e >> 7) * 129 + (e & 127)] = g_V[base + e];
        e = l + 256;
        s_pv[(e >> 7) * 129 + (e & 127)] = g_V[base + e];
    }
    __syncthreads();

    const float* __restrict__ dimg = depth + (size_t)n * (IMG * IMG);
    const unsigned short* __restrict__ Ubase = &g_U[(n << 14) + ixg * 16 + ix_l];
    const int   row   = ix_l * 4 + iy_l;   // all 64 values within a wave
    const float trunc = 1.0f / 128.0f;

#pragma unroll
    for (int j = 0; j < 8; ++j) {
        float4 acc; float* ap = &acc.x;
#pragma unroll
        for (int jj = 0; jj < 4; ++jj) {
            const int   iz = izq * 32 + j * 4 + jj;     // wave-uniform
            const float zc = s_zc[iz];                  // broadcast
            const int   pv = s_pv[iy_l * 129 + iz];     // 4-addr broadcast
            const int   pu = Ubase[iz << 7];            // 32B/instr, L1-hot
            const int   ui = pu & 0x1FF;
            const int   vrow = pv & 0x3FFFF;
            const int   ok = (pv >> 30) & (pu >> 15) & 1;
            const float d  = dimg[vrow + ui];           // L2-resident gather
            const float tdf = fminf(fabsf(zc - d), trunc);
            ap[jj] = (ok && d > 0.0f) ? (1.0f - 128.0f * tdf) : 0.0f;
        }
        *(float4*)&s_tile[row * TS + izq * 32 + j * 4] = acc;  // b128, floor
    }
    __syncthreads();

    // store: thread t, step s -> float4 f4i = t + 256*s over the 8192-elem
    // tile in (ix, iy, iz) order: every wave instr = 1KB contiguous global.
    const size_t base = ((size_t)(n * RES + ixg * 16) * RES + iyg * 4) * RES;
#pragma unroll
    for (int s = 0; s < 8; ++s) {
        const int f   = (l + 256 * s) * 4;
        const int ixl = f >> 9;            // 0..15
        const int rem = f & 511;           // (iy_l*128 + iz)
        const float4 val = *(const float4*)&s_tile[(ixl * 4 + (rem >> 7)) * TS + (rem & 127)];
        *(float4*)&out[base + (size_t)ixl * (RES * RES) + rem] = val;
    }
}

extern "C" void kernel_launch(void* const* d_in, const int* in_sizes, int n_in,
                              void* d_out, int out_size, void* d_ws, size_t ws_size,
                              hipStream_t stream) {
    const float* depth = (const float*)d_in[0];
    const float* fl    = (const float*)d_in[1];
    const float* cd    = (const float*)d_in[2];
    float* out         = (float*)d_out;

    const int N = in_sizes[1];                     // fl is (N,1)
    const int tab_total = N * RES * RES;
    cbp_tables<<<(tab_total + 255) / 256, 256, 0, stream>>>(fl, cd, tab_total);

    cbp_main<<<N * 256, 256, 0, stream>>>(depth, cd, out, N);
}